// Round 1
// 640.208 us; speedup vs baseline: 1.0010x; 1.0010x over previous
//
#include <hip/hip_runtime.h>
#include <cstdint>
#include <cstddef>

#define B_SZ 65536

typedef __attribute__((ext_vector_type(8))) short bf16x8;
typedef __attribute__((ext_vector_type(8))) unsigned short u16x8;
typedef __attribute__((ext_vector_type(4))) float f32x4;

__device__ __forceinline__ unsigned short f2bf(float f) {
  union { float f; uint32_t u; } v; v.f = f;
  uint32_t u = v.u;
  uint32_t r = (u + 0x7FFFu + ((u >> 16) & 1u)) >> 16;  // RNE
  return (unsigned short)r;
}

// Pack W as bf16 [1024, 512]; packed row rho = bn*256 + wc*64 + gate*16 + hh
// <- W_gate source row (bn*64 + wc*16 + hh). Puts the 4 gates of each h in one
// wave's 4 n-fragments (gi == gate), for BN=256 blocks (bn in 0..3).
__global__ __launch_bounds__(256) void pack_w_kernel(const float* __restrict__ Wf,
                                                     const float* __restrict__ Wi,
                                                     const float* __restrict__ Wo,
                                                     const float* __restrict__ Wg,
                                                     unsigned short* __restrict__ out) {
  int i = blockIdx.x * 256 + threadIdx.x;  // chunk in [0, 1024*64)
  int rho = i >> 6, c = i & 63;
  int bn = rho >> 8;
  int r = rho & 255;
  int wc = r >> 6, gate = (r >> 4) & 3, hh = r & 15;
  int srow = (bn << 6) + (wc << 4) + hh;
  const float* W = (gate == 0) ? Wf : (gate == 1) ? Wi : (gate == 2) ? Wo : Wg;
  const float* src = W + (size_t)srow * 512 + ((size_t)c << 3);
  float4 v0 = ((const float4*)src)[0];
  float4 v1 = ((const float4*)src)[1];
  u16x8 o;
  o[0] = f2bf(v0.x); o[1] = f2bf(v0.y); o[2] = f2bf(v0.z); o[3] = f2bf(v0.w);
  o[4] = f2bf(v1.x); o[5] = f2bf(v1.y); o[6] = f2bf(v1.z); o[7] = f2bf(v1.w);
  *((u16x8*)(out + ((size_t)i << 3))) = o;
}

__device__ __forceinline__ float sigmoid_f(float x) {
  return __builtin_amdgcn_rcpf(1.f + __expf(-x));
}
__device__ __forceinline__ float tanh_f(float x) {
  return 1.f - 2.f * __builtin_amdgcn_rcpf(__expf(2.f * x) + 1.f);
}

// Fused pack+GEMM+LSTM. Tile BM=128 x BN=256 x BK=64, 512 threads = 8 waves
// (2 m-halves x 4 n-quarters), each wave 64x64 via 4x4 mfma_f32_16x16x32_bf16.
// A = [x|h_prev] read as fp32 and converted in-register (no pack_a kernel).
// Double-buffered LDS, 2-phase prefetch: stage tile kt+1 before computing kt,
// single barrier per K-step (compiler's vmcnt(0) drain lands after the MFMAs).
// Block mapping groups the 4 bn-blocks of each m-tile on one XCD: per-XCD
// working set (8 m-tiles x 256KB A-panel + 1MB B) ~ 3MB fits the 4MB L2, so
// A is fetched from HBM once.
__global__ __launch_bounds__(512, 2) void lstm_fused_kernel(
    const float* __restrict__ X, const float* __restrict__ Hp,
    const unsigned short* __restrict__ Wb, const float* __restrict__ c_prev,
    const float* __restrict__ bf_, const float* __restrict__ bi_,
    const float* __restrict__ bo_, const float* __restrict__ bg_,
    float* __restrict__ out) {
  __shared__ __align__(16) unsigned short As[2][128 * 64];  // 2 x 16 KiB
  __shared__ __align__(16) unsigned short Bs[2][256 * 64];  // 2 x 32 KiB

  // XCD-grouped decode: xcd = L&7 (linear round-robin heuristic), each XCD owns
  // m-tiles [64*xcd, 64*xcd+64); the 4 bn of an m-tile are consecutive slots.
  const int L = blockIdx.x;
  const int xcd = L & 7, slot = L >> 3;
  const int mt = (xcd << 6) + (slot >> 2);
  const int bn = slot & 3;  // n-block of 64 h
  const int m0 = mt << 7;

  const int t = threadIdx.x;
  const int lane = t & 63, w = t >> 6;
  const int r15 = lane & 15, quad = lane >> 4;
  const int mbase = (w >> 2) << 6;  // m offset within tile: 0 or 64
  const int nbase = (w & 3) << 6;   // n_local offset: 0,64,128,192

  // Epilogue constants hoisted so bias-load latency hides under the K-loop.
  const int h = (bn << 6) + ((w & 3) << 4) + r15;  // global h in [0,256)
  const float Bf = bf_[h], Bi = bi_[h], Bo = bo_[h], Bg = bg_[h];

  // A staging geometry: 1024 16B-chunks (128 rows x 8 chunks), 2 per thread.
  // Slot st holds global chunk st^(row&7) (same XOR swizzle as the B side, so
  // the ds_read_b128 fragment reads stay ~conflict-free).
  const int la0 = t, la1 = t + 512;
  const int ar0 = la0 >> 3, ar1 = la1 >> 3;
  const int ac0 = (la0 & 7) ^ (ar0 & 7), ac1 = (la1 & 7) ^ (ar1 & 7);

  f32x4 zero = {0.f, 0.f, 0.f, 0.f};
  f32x4 acc[4][4];
#pragma unroll
  for (int a = 0; a < 4; ++a)
#pragma unroll
    for (int b = 0; b < 4; ++b) acc[a][b] = zero;

  float4 av[4];  // in-flight A fp32 (2 chunks x 2 float4)

  auto load_A = [&](int kt) {
    // K boundary at 256 == 4 K-steps: steps 0..3 from x, 4..7 from h_prev.
    const float* src = (kt < 4) ? X : Hp;
    const int kcol = (kt & 3) << 6;
    const float* p0 = src + (size_t)(m0 + ar0) * 256 + kcol + (ac0 << 3);
    const float* p1 = src + (size_t)(m0 + ar1) * 256 + kcol + (ac1 << 3);
    av[0] = ((const float4*)p0)[0];
    av[1] = ((const float4*)p0)[1];
    av[2] = ((const float4*)p1)[0];
    av[3] = ((const float4*)p1)[1];
  };

  auto write_A = [&](int buf) {
    u16x8 o0, o1;
    o0[0] = f2bf(av[0].x); o0[1] = f2bf(av[0].y); o0[2] = f2bf(av[0].z); o0[3] = f2bf(av[0].w);
    o0[4] = f2bf(av[1].x); o0[5] = f2bf(av[1].y); o0[6] = f2bf(av[1].z); o0[7] = f2bf(av[1].w);
    o1[0] = f2bf(av[2].x); o1[1] = f2bf(av[2].y); o1[2] = f2bf(av[2].z); o1[3] = f2bf(av[2].w);
    o1[4] = f2bf(av[3].x); o1[5] = f2bf(av[3].y); o1[6] = f2bf(av[3].z); o1[7] = f2bf(av[3].w);
    *((u16x8*)&As[buf][la0 << 3]) = o0;
    *((u16x8*)&As[buf][la1 << 3]) = o1;
  };

  auto stage_B = [&](int buf, int kt) {
    const int k0 = kt << 6;
#pragma unroll
    for (int jj = 0; jj < 4; ++jj) {
      int l = (jj << 9) + t;         // 16B-chunk id in [0, 2048)
      int row = l >> 3, st = l & 7;  // LDS chunk slot
      int c = st ^ (row & 7);        // global chunk fetched into that slot
      const unsigned short* gb =
          Wb + (size_t)((bn << 8) + row) * 512 + k0 + (c << 3);
      __builtin_amdgcn_global_load_lds(
          (const __attribute__((address_space(1))) void*)gb,
          (__attribute__((address_space(3))) void*)(&Bs[buf][l << 3]), 16, 0, 0);
    }
  };

  auto compute = [&](int buf) {
#pragma unroll
    for (int ks = 0; ks < 2; ++ks) {
      bf16x8 af[4], bfr[4];
      const int ch = (ks << 2) + quad;
#pragma unroll
      for (int mi = 0; mi < 4; ++mi) {
        int row = mbase + (mi << 4) + r15;
        af[mi] = *((const bf16x8*)&As[buf][(row << 6) + ((ch ^ (row & 7)) << 3)]);
      }
#pragma unroll
      for (int gi = 0; gi < 4; ++gi) {
        int row = nbase + (gi << 4) + r15;
        bfr[gi] = *((const bf16x8*)&Bs[buf][(row << 6) + ((ch ^ (row & 7)) << 3)]);
      }
#pragma unroll
      for (int mi = 0; mi < 4; ++mi)
#pragma unroll
        for (int gi = 0; gi < 4; ++gi)
          acc[mi][gi] = __builtin_amdgcn_mfma_f32_16x16x32_bf16(
              af[mi], bfr[gi], acc[mi][gi], 0, 0, 0);
    }
  };

  // Prologue: stage tile 0 into buffer 0 (latency exposed once).
  load_A(0);
  stage_B(0, 0);
  write_A(0);
  __syncthreads();

#pragma unroll
  for (int kt = 0; kt < 8; ++kt) {
    const int cur = kt & 1, nxt = cur ^ 1;
    if (kt < 7) {
      load_A(kt + 1);      // fp32 A -> regs (async under MFMAs)
      stage_B(nxt, kt + 1);  // bf16 B -> LDS direct (async under MFMAs)
    }
    compute(cur);
    if (kt < 7) write_A(nxt);  // cvt + ds_write after compute; vmcnt wait here
    __syncthreads();           // single drain per K-step, after the MFMAs
  }

  // Fused LSTM epilogue: lane holds f,i,o,g pre-activations for its (m,h).
  const size_t S = (size_t)B_SZ * 256;
#pragma unroll
  for (int mi = 0; mi < 4; ++mi) {
    const int mr0 = m0 + mbase + (mi << 4) + (quad << 2);
#pragma unroll
    for (int r = 0; r < 4; ++r) {
      const int m = mr0 + r;
      float F = acc[mi][0][r] + Bf;
      float I = acc[mi][1][r] + Bi;
      float O = acc[mi][2][r] + Bo;
      float G = acc[mi][3][r] + Bg;
      float f = sigmoid_f(F);
      float ii = sigmoid_f(I);
      float o = sigmoid_f(O);
      float g = tanh_f(G);
      size_t base = (size_t)m * 256 + h;
      float cp = c_prev[base];
      float ct = f * cp + ii * g;
      float ht = o * tanh_f(ct);
      out[base] = ht;
      out[S + base] = ct;
      out[2 * S + base] = f;
      out[3 * S + base] = ii;
      out[4 * S + base] = o;
      out[5 * S + base] = g;
    }
  }
}

extern "C" void kernel_launch(void* const* d_in, const int* in_sizes, int n_in,
                              void* d_out, int out_size, void* d_ws, size_t ws_size,
                              hipStream_t stream) {
  const float* x   = (const float*)d_in[0];
  const float* hp  = (const float*)d_in[1];
  const float* cp  = (const float*)d_in[2];
  const float* Wf  = (const float*)d_in[3];
  const float* bf_ = (const float*)d_in[4];
  const float* Wi  = (const float*)d_in[5];
  const float* bi_ = (const float*)d_in[6];
  const float* Wo  = (const float*)d_in[7];
  const float* bo_ = (const float*)d_in[8];
  const float* Wg  = (const float*)d_in[9];
  const float* bg_ = (const float*)d_in[10];
  float* out = (float*)d_out;

  unsigned short* Wb = (unsigned short*)d_ws;  // 1 MiB packed weights

  pack_w_kernel<<<dim3(256), dim3(256), 0, stream>>>(Wf, Wi, Wo, Wg, Wb);
  lstm_fused_kernel<<<dim3(2048), dim3(512), 0, stream>>>(x, hp, Wb, cp, bf_, bi_,
                                                          bo_, bg_, out);
}